// Round 5
// baseline (52832.959 us; speedup 1.0000x reference)
//
#include <hip/hip_runtime.h>
#include <hip/hip_bf16.h>
#include <math.h>

#define NB 64
#define NT 512
#define NDIN 256
#define NH 1024
#define NG 4096
#define NDOUT 256

#define GRID 512
#define SK 15          // z splitK slices (32 ct * 15 = 480 z blocks)
#define UZ 8           // units per z slice (120/15)
#define NZB 480

typedef __attribute__((ext_vector_type(8))) short short8;
typedef __attribute__((ext_vector_type(4))) float float4v;

__device__ __forceinline__ float sigf(float v) { return 1.0f / (1.0f + expf(-v)); }

__device__ __forceinline__ unsigned short bf_hi(float v, float* back) {
    __hip_bfloat16 b = __float2bfloat16(v);
    *back = __bfloat162float(b);
    union { __hip_bfloat16 b; unsigned short u; } cv; cv.b = b;
    return cv.u;
}

__global__ void zero_kernel(float* __restrict__ p, int n) {
    int i = blockIdx.x * 256 + threadIdx.x;
    if (i < n) p[i] = 0.0f;
}

// W (= [Wx;Wh], 1280 x 4096) -> B-frag order [nb(256)][ku(40)][lane(64)][j(8)], hi/lo
__global__ void packW_kernel(const float* __restrict__ Wx, const float* __restrict__ Wh,
                             unsigned short* __restrict__ W0f, unsigned short* __restrict__ W1f) {
    int e = blockIdx.x * 256 + threadIdx.x;
    if (e >= 1280 * 4096) return;
    int k = e >> 12, n = e & 4095;
    float w = (k < NDIN) ? Wx[(size_t)k * NG + n] : Wh[(size_t)(k - NDIN) * NG + n];
    float back;
    unsigned short w0 = bf_hi(w, &back);
    unsigned short w1 = bf_hi(w - back, &back);
    int nb = n >> 4, nl = n & 15, ku = k >> 5, kr = k & 31;
    int lane = (kr >> 3) * 16 + nl, j = kr & 7;
    size_t off = (((size_t)nb * 40 + ku) * 64 + lane) * 8 + j;
    W0f[off] = w0; W1f[off] = w1;
}

// x ([64][512][256]) -> A-frag order [t][ku(8)][mb(4)][lane(64)][j(8)], hi/lo
__global__ void packX_kernel(const float* __restrict__ x,
                             unsigned short* __restrict__ xf0, unsigned short* __restrict__ xf1) {
    int e = blockIdx.x * 256 + threadIdx.x;
    if (e >= NB * NT * NDIN) return;
    int k = e & 255, t = (e >> 8) & 511, m = e >> 17;
    float v = x[e];
    float back;
    unsigned short a0 = bf_hi(v, &back);
    unsigned short a1 = bf_hi(v - back, &back);
    int ku = k >> 5, kr = k & 31, mb = m >> 4;
    int lane = (kr >> 3) * 16 + (m & 15), j = kr & 7;
    size_t off = ((((size_t)t * 8 + ku) * 4 + mb) * 64 + lane) * 8 + j;
    xf0[off] = a0; xf1[off] = a1;
}

// Wo (1024 x 256) -> B-frag order [nb(16)][ku(32)][lane(64)][j(8)], hi/lo
__global__ void packWo_kernel(const float* __restrict__ Wo,
                              unsigned short* __restrict__ Wo0f, unsigned short* __restrict__ Wo1f) {
    int e = blockIdx.x * 256 + threadIdx.x;
    if (e >= NH * NDOUT) return;
    int k = e >> 8, n = e & 255;
    float w = Wo[e];
    float back;
    unsigned short w0 = bf_hi(w, &back);
    unsigned short w1 = bf_hi(w - back, &back);
    int nb = n >> 4, nl = n & 15, ku = k >> 5, kr = k & 31;
    int lane = (kr >> 3) * 16 + nl, j = kr & 7;
    size_t off = (((size_t)nb * 32 + ku) * 64 + lane) * 8 + j;
    Wo0f[off] = w0; Wo1f[off] = w1;
}

// Hierarchical grid barrier: 16 groups of 32 blocks -> root. Monotonic epochs.
__device__ __forceinline__ void gridbar(unsigned* bar, unsigned k) {
    __syncthreads();
    if (threadIdx.x == 0) {
        __threadfence();   // release
        const int grp = blockIdx.x >> 5;
        unsigned* gcnt = bar + 64 + grp * 32;
        unsigned* grel = bar + 64 + 512 + grp * 32;
        unsigned a = __hip_atomic_fetch_add(gcnt, 1u, __ATOMIC_ACQ_REL, __HIP_MEMORY_SCOPE_AGENT) + 1;
        if (a == k * 32u) {   // group leader
            unsigned r = __hip_atomic_fetch_add(bar, 1u, __ATOMIC_ACQ_REL, __HIP_MEMORY_SCOPE_AGENT) + 1;
            if (r == k * 16u) {
                __hip_atomic_store(bar + 8, k, __ATOMIC_RELEASE, __HIP_MEMORY_SCOPE_AGENT);
            } else {
                while (__hip_atomic_load(bar + 8, __ATOMIC_RELAXED, __HIP_MEMORY_SCOPE_AGENT) < k)
                    __builtin_amdgcn_s_sleep(1);
            }
            __hip_atomic_store(grel, k, __ATOMIC_RELEASE, __HIP_MEMORY_SCOPE_AGENT);
        } else {
            while (__hip_atomic_load(grel, __ATOMIC_RELAXED, __HIP_MEMORY_SCOPE_AGENT) < k)
                __builtin_amdgcn_s_sleep(1);
        }
        __threadfence();   // acquire
    }
    __syncthreads();
}

__global__ __launch_bounds__(256, 2) void persist(
    const unsigned short* __restrict__ W0f, const unsigned short* __restrict__ W1f,
    const unsigned short* __restrict__ xf0, const unsigned short* __restrict__ xf1,
    const unsigned short* __restrict__ Wo0f, const unsigned short* __restrict__ Wo1f,
    unsigned short* __restrict__ hf, float* __restrict__ cst,
    float* __restrict__ zpart, float* __restrict__ opart, unsigned* __restrict__ bar,
    const float* __restrict__ bias, const float* __restrict__ bo,
    float* __restrict__ out)
{
    __shared__ const unsigned short* tA[48];
    __shared__ const unsigned short* tW[48];
    __shared__ float zs[4 * 260];

    const int bid = blockIdx.x;
    const int tid = threadIdx.x;
    const int lane = tid & 63;
    const int w = tid >> 6;

    const bool isZ = bid < NZB;
    const int ct = bid / SK, s = bid % SK;          // z role
    const int pb = bid - NZB;                        // proj role
    const int pnb = pb >> 1, pksl = pb & 1;

    for (int t = 0; t <= NT; ++t) {
        const int buf = t & 1;
        // ---- build per-step address tables (LDS) ----
        if (isZ) {
            if (t < NT) {
                for (int i = tid; i < UZ; i += 256) {
                    int u = s * UZ + i, p = u / 40, ku = u % 40;
                    const unsigned short* Ap;
                    if (ku < 8) {
                        const unsigned short* xf = (p == 2) ? xf1 : xf0;
                        Ap = xf + (((size_t)t * 8 + ku) * 4) * 512;
                    } else {
                        int v = (p == 2);
                        Ap = hf + (((size_t)(v * 2 + buf) * 32 + (ku - 8)) * 4) * 512;
                    }
                    tA[i] = Ap;
                    tW[i] = ((p == 1) ? W1f : W0f) + (size_t)ku * 512;
                }
            }
        } else {
            for (int i = tid; i < 48; i += 256) {
                int u = pksl * 48 + i, q = u / 32, ku = u % 32;
                int v = (q == 2);
                tA[i] = hf + (((size_t)(v * 2 + buf) * 32 + ku) * 4) * 512;
                tW[i] = ((q == 1) ? Wo1f : Wo0f) + (size_t)pnb * 32 * 512 + (size_t)ku * 512;
            }
        }
        __syncthreads();

        // ---- phase A ----
        if (isZ) {
            if (t < NT) {
                const int nb0 = ct * 8 + w * 2;
                float4v acc[4][2];
                #pragma unroll
                for (int mb = 0; mb < 4; ++mb)
                    #pragma unroll
                    for (int nl = 0; nl < 2; ++nl)
                        acc[mb][nl] = (float4v){0.f, 0.f, 0.f, 0.f};

                #pragma unroll
                for (int i = 0; i < UZ; ++i) {
                    const unsigned short* Ap = tA[i];
                    const unsigned short* Wp = tW[i];
                    short8 A[4], B[2];
                    #pragma unroll
                    for (int mb = 0; mb < 4; ++mb)
                        A[mb] = *(const short8*)(Ap + mb * 512 + lane * 8);
                    #pragma unroll
                    for (int nl = 0; nl < 2; ++nl)
                        B[nl] = *(const short8*)(Wp + (size_t)(nb0 + nl) * 20480 + lane * 8);
                    #pragma unroll
                    for (int mb = 0; mb < 4; ++mb)
                        #pragma unroll
                        for (int nl = 0; nl < 2; ++nl)
                            acc[mb][nl] = __builtin_amdgcn_mfma_f32_16x16x32_bf16(
                                A[mb], B[nl], acc[mb][nl], 0, 0, 0);
                }
                const int q4 = lane >> 4, nl16 = lane & 15;
                #pragma unroll
                for (int mb = 0; mb < 4; ++mb)
                    #pragma unroll
                    for (int nl = 0; nl < 2; ++nl)
                        #pragma unroll
                        for (int r = 0; r < 4; ++r)
                            zpart[((size_t)(s * 64 + mb * 16 + q4 * 4 + r)) * NG
                                  + (nb0 + nl) * 16 + nl16] = acc[mb][nl][r];
            }
        } else {
            // projection of h_t (hf[buf]) -> opart slice pksl
            float4v pacc = (float4v){0.f, 0.f, 0.f, 0.f};
            #pragma unroll 6
            for (int i = 0; i < 48; ++i) {
                short8 A = *(const short8*)(tA[i] + w * 512 + lane * 8);
                short8 Bv = *(const short8*)(tW[i] + lane * 8);
                pacc = __builtin_amdgcn_mfma_f32_16x16x32_bf16(A, Bv, pacc, 0, 0, 0);
            }
            const int q4 = lane >> 4, nl16 = lane & 15;
            #pragma unroll
            for (int r = 0; r < 4; ++r)
                opart[((size_t)(pksl * 64 + w * 16 + q4 * 4 + r)) * NDOUT
                      + pnb * 16 + nl16] = pacc[r];
        }

        gridbar(bar, 2 * t + 1);

        // ---- phase B: combine gates ----
        if (t < NT && bid < 256) {
            const int m = bid >> 2, jc = (bid & 3) << 8;
            for (int rep = 0; rep < 4; ++rep) {
                const int j = jc + rep * 64 + lane;
                float sum = 0.f;
                #pragma unroll
                for (int sI = 0; sI < SK; ++sI)
                    sum += zpart[((size_t)(sI * 64 + m)) * NG + w * NH + j];
                zs[w * 260 + rep * 64 + lane] = sum;
            }
            __syncthreads();
            {
                const int jl = tid, j = jc + jl;
                float zi = zs[0 * 260 + jl] + bias[j];
                float zf = zs[1 * 260 + jl] + bias[NH + j];
                float zg = zs[2 * 260 + jl] + bias[2 * NH + j];
                float zo = zs[3 * 260 + jl] + bias[3 * NH + j];
                float iv = sigf(zi), fv = sigf(zf), gv = tanhf(zg), ov = sigf(zo);
                const size_t ci = (size_t)m * NH + j;
                float cv = fv * cst[ci] + iv * gv;
                cst[ci] = cv;
                float hv = ov * tanhf(cv);
                float back;
                unsigned short h0 = bf_hi(hv, &back);
                unsigned short h1 = bf_hi(hv - back, &back);
                const int nbuf = (t + 1) & 1;
                int ku = j >> 5, kr = j & 31, mb2 = m >> 4;
                int lane2 = (kr >> 3) * 16 + (m & 15), jj = kr & 7;
                size_t base = (((size_t)nbuf * 32 + ku) * 4 + mb2) * 512 + lane2 * 8 + jj;
                hf[base] = h0;
                hf[base + 131072] = h1;   // v=1 stride = 2*32*4*512
            }
        }
        // ---- phase B: out reduce (row t-1) on last 32 blocks ----
        if (t >= 1 && bid >= GRID - 32) {
            const int b0 = (bid - (GRID - 32)) * 512;
            #pragma unroll
            for (int rr = 0; rr < 2; ++rr) {
                const int e = b0 + rr * 256 + tid;
                const int m = e >> 8, oc = e & 255;
                float v = opart[(size_t)m * NDOUT + oc]
                        + opart[(size_t)(64 + m) * NDOUT + oc] + bo[oc];
                out[((size_t)m * NT + (t - 1)) * NDOUT + oc] = fmaxf(v, 0.f);
            }
        }

        gridbar(bar, 2 * t + 2);
    }
}

extern "C" void kernel_launch(void* const* d_in, const int* in_sizes, int n_in,
                              void* d_out, int out_size, void* d_ws, size_t ws_size,
                              hipStream_t stream) {
    const float* x  = (const float*)d_in[0];
    const float* Wx = (const float*)d_in[1];
    const float* Wh = (const float*)d_in[2];
    const float* b  = (const float*)d_in[3];
    const float* Wo = (const float*)d_in[4];
    const float* bo = (const float*)d_in[5];
    float* out = (float*)d_out;
    char* ws = (char*)d_ws;

    size_t off = 0;
    unsigned* bar = (unsigned*)(ws + off);       off += 8192;
    float* cst    = (float*)(ws + off);          off += (size_t)NB * NH * 4;
    unsigned short* hf = (unsigned short*)(ws + off); off += (size_t)2 * 2 * 32 * 4 * 512 * 2;
    size_t zero_floats = off / 4;                 // bar + c + hf zeroed
    float* opart = (float*)(ws + off);           off += (size_t)2 * NB * NDOUT * 4;
    float* zpart = (float*)(ws + off);           off += (size_t)SK * NB * NG * 4;
    unsigned short* W0f = (unsigned short*)(ws + off); off += (size_t)1280 * 4096 * 2;
    unsigned short* W1f = (unsigned short*)(ws + off); off += (size_t)1280 * 4096 * 2;
    unsigned short* Wo0f = (unsigned short*)(ws + off); off += (size_t)NH * NDOUT * 2;
    unsigned short* Wo1f = (unsigned short*)(ws + off); off += (size_t)NH * NDOUT * 2;
    unsigned short* xf0 = (unsigned short*)(ws + off); off += (size_t)NB * NT * NDIN * 2;
    unsigned short* xf1 = (unsigned short*)(ws + off); off += (size_t)NB * NT * NDIN * 2;

    zero_kernel<<<(int)((zero_floats + 255) / 256), 256, 0, stream>>>((float*)ws, (int)zero_floats);
    packW_kernel<<<(1280 * 4096 + 255) / 256, 256, 0, stream>>>(Wx, Wh, W0f, W1f);
    packX_kernel<<<(NB * NT * NDIN + 255) / 256, 256, 0, stream>>>(x, xf0, xf1);
    packWo_kernel<<<(NH * NDOUT + 255) / 256, 256, 0, stream>>>(Wo, Wo0f, Wo1f);

    persist<<<GRID, 256, 0, stream>>>(W0f, W1f, xf0, xf1, Wo0f, Wo1f, hf, cst,
                                      zpart, opart, bar, b, bo, out);
}

// Round 9
// 9333.921 us; speedup vs baseline: 5.6603x; 5.6603x over previous
//
#include <hip/hip_runtime.h>
#include <hip/hip_bf16.h>
#include <math.h>

#define NB 64
#define NT 512
#define NDIN 256
#define NH 1024
#define NG 4096
#define NDOUT 256

#define SK 15          // z splitK slices (32 ct * 15 = 480 z blocks)
#define UZ 8           // units per z slice (120/15)
#define NZB 480
#define GRIDA 512      // 480 z + 32 proj
#define GRIDB 288      // 256 combine + 32 out-reduce

typedef __attribute__((ext_vector_type(8))) short short8;
typedef __attribute__((ext_vector_type(4))) float float4v;

__device__ __forceinline__ float sigf(float v) { return 1.0f / (1.0f + expf(-v)); }

__device__ __forceinline__ unsigned short bf_hi(float v, float* back) {
    __hip_bfloat16 b = __float2bfloat16(v);
    *back = __bfloat162float(b);
    union { __hip_bfloat16 b; unsigned short u; } cv; cv.b = b;
    return cv.u;
}

__global__ void zero_kernel(float* __restrict__ p, int n) {
    int i = blockIdx.x * 256 + threadIdx.x;
    if (i < n) p[i] = 0.0f;
}

// W (= [Wx;Wh], 1280 x 4096) -> B-frag order [nb(256)][ku(40)][lane(64)][j(8)], hi/lo
__global__ void packW_kernel(const float* __restrict__ Wx, const float* __restrict__ Wh,
                             unsigned short* __restrict__ W0f, unsigned short* __restrict__ W1f) {
    int e = blockIdx.x * 256 + threadIdx.x;
    if (e >= 1280 * 4096) return;
    int k = e >> 12, n = e & 4095;
    float w = (k < NDIN) ? Wx[(size_t)k * NG + n] : Wh[(size_t)(k - NDIN) * NG + n];
    float back;
    unsigned short w0 = bf_hi(w, &back);
    unsigned short w1 = bf_hi(w - back, &back);
    int nb = n >> 4, nl = n & 15, ku = k >> 5, kr = k & 31;
    int lane = (kr >> 3) * 16 + nl, j = kr & 7;
    size_t off = (((size_t)nb * 40 + ku) * 64 + lane) * 8 + j;
    W0f[off] = w0; W1f[off] = w1;
}

// x ([64][512][256]) -> A-frag order [t][ku(8)][mb(4)][lane(64)][j(8)], hi/lo
__global__ void packX_kernel(const float* __restrict__ x,
                             unsigned short* __restrict__ xf0, unsigned short* __restrict__ xf1) {
    int e = blockIdx.x * 256 + threadIdx.x;
    if (e >= NB * NT * NDIN) return;
    int k = e & 255, t = (e >> 8) & 511, m = e >> 17;
    float v = x[e];
    float back;
    unsigned short a0 = bf_hi(v, &back);
    unsigned short a1 = bf_hi(v - back, &back);
    int ku = k >> 5, kr = k & 31, mb = m >> 4;
    int lane = (kr >> 3) * 16 + (m & 15), j = kr & 7;
    size_t off = ((((size_t)t * 8 + ku) * 4 + mb) * 64 + lane) * 8 + j;
    xf0[off] = a0; xf1[off] = a1;
}

// Wo (1024 x 256) -> B-frag order [nb(16)][ku(32)][lane(64)][j(8)], hi/lo
__global__ void packWo_kernel(const float* __restrict__ Wo,
                              unsigned short* __restrict__ Wo0f, unsigned short* __restrict__ Wo1f) {
    int e = blockIdx.x * 256 + threadIdx.x;
    if (e >= NH * NDOUT) return;
    int k = e >> 8, n = e & 255;
    float w = Wo[e];
    float back;
    unsigned short w0 = bf_hi(w, &back);
    unsigned short w1 = bf_hi(w - back, &back);
    int nb = n >> 4, nl = n & 15, ku = k >> 5, kr = k & 31;
    int lane = (kr >> 3) * 16 + nl, j = kr & 7;
    size_t off = (((size_t)nb * 32 + ku) * 64 + lane) * 8 + j;
    Wo0f[off] = w0; Wo1f[off] = w1;
}

// ---- Kernel A (per step): z-GEMM splitK (480 blocks) + proj MFMA (32 blocks)
// All cross-step data arrives via the kernel boundary (HW-coherent).
__global__ __launch_bounds__(256, 2) void lstm_a(
    const unsigned short* __restrict__ W0f, const unsigned short* __restrict__ W1f,
    const unsigned short* __restrict__ xf0, const unsigned short* __restrict__ xf1,
    const unsigned short* __restrict__ Wo0f, const unsigned short* __restrict__ Wo1f,
    const unsigned short* __restrict__ hf,
    float* __restrict__ zpart, float* __restrict__ opart,
    int t, int gates)
{
    __shared__ const unsigned short* tA[48];
    __shared__ const unsigned short* tW[48];

    const int bid = blockIdx.x, tid = threadIdx.x;
    const int lane = tid & 63, w = tid >> 6;
    const int buf = t & 1;
    const bool isZ = gates && (bid < NZB);

    if (isZ) {
        const int ct = bid / SK, s = bid % SK;
        const int nb0 = ct * 8 + w * 2;
        // per-step address table (round-5 verified)
        for (int i = tid; i < UZ; i += 256) {
            int u = s * UZ + i, p = u / 40, ku = u % 40;
            const unsigned short* Ap;
            if (ku < 8) {
                const unsigned short* xf = (p == 2) ? xf1 : xf0;
                Ap = xf + (((size_t)t * 8 + ku) * 4) * 512;
            } else {
                int v = (p == 2);
                Ap = hf + (((size_t)(v * 2 + buf) * 32 + (ku - 8)) * 4) * 512;
            }
            tA[i] = Ap;
            tW[i] = ((p == 1) ? W1f : W0f) + (size_t)ku * 512;
        }
        __syncthreads();

        float4v acc[4][2];
        #pragma unroll
        for (int mb = 0; mb < 4; ++mb)
            #pragma unroll
            for (int nl = 0; nl < 2; ++nl)
                acc[mb][nl] = (float4v){0.f, 0.f, 0.f, 0.f};

        #pragma unroll
        for (int i = 0; i < UZ; ++i) {
            const unsigned short* Ap = tA[i];
            const unsigned short* Wp = tW[i];
            short8 A[4], B[2];
            #pragma unroll
            for (int mb = 0; mb < 4; ++mb)
                A[mb] = *(const short8*)(Ap + mb * 512 + lane * 8);
            #pragma unroll
            for (int nl = 0; nl < 2; ++nl)
                B[nl] = *(const short8*)(Wp + (size_t)(nb0 + nl) * 20480 + lane * 8);
            #pragma unroll
            for (int mb = 0; mb < 4; ++mb)
                #pragma unroll
                for (int nl = 0; nl < 2; ++nl)
                    acc[mb][nl] = __builtin_amdgcn_mfma_f32_16x16x32_bf16(
                        A[mb], B[nl], acc[mb][nl], 0, 0, 0);
        }
        const int q4 = lane >> 4, nl16 = lane & 15;
        #pragma unroll
        for (int mb = 0; mb < 4; ++mb)
            #pragma unroll
            for (int nl = 0; nl < 2; ++nl)
                #pragma unroll
                for (int r = 0; r < 4; ++r)
                    zpart[((size_t)(s * 64 + mb * 16 + q4 * 4 + r)) * NG
                          + (nb0 + nl) * 16 + nl16] = acc[mb][nl][r];
    } else {
        // projection of hf[buf] (= h_t) -> opart  (round-5 verified)
        const int pb = gates ? (bid - NZB) : bid;
        if (pb < 0 || pb >= 32) return;
        const int pnb = pb >> 1, pksl = pb & 1;
        for (int i = tid; i < 48; i += 256) {
            int u = pksl * 48 + i, q = u / 32, ku = u % 32;
            int v = (q == 2);
            tA[i] = hf + (((size_t)(v * 2 + buf) * 32 + ku) * 4) * 512;
            tW[i] = ((q == 1) ? Wo1f : Wo0f) + (size_t)pnb * 32 * 512 + (size_t)ku * 512;
        }
        __syncthreads();

        float4v pacc = (float4v){0.f, 0.f, 0.f, 0.f};
        #pragma unroll 6
        for (int i = 0; i < 48; ++i) {
            short8 A = *(const short8*)(tA[i] + w * 512 + lane * 8);
            short8 Bv = *(const short8*)(tW[i] + lane * 8);
            pacc = __builtin_amdgcn_mfma_f32_16x16x32_bf16(A, Bv, pacc, 0, 0, 0);
        }
        const int q4 = lane >> 4, nl16 = lane & 15;
        #pragma unroll
        for (int r = 0; r < 4; ++r)
            opart[((size_t)(pksl * 64 + w * 16 + q4 * 4 + r)) * NDOUT
                  + pnb * 16 + nl16] = pacc[r];
    }
}

// ---- Kernel B (per step): gate combine -> cst, hf[next] (256 blocks)
//      + out-reduce of opart -> out row t-1 (32 blocks)
__global__ __launch_bounds__(256) void lstm_b(
    const float* __restrict__ zpart, const float* __restrict__ opart,
    const float* __restrict__ bias, const float* __restrict__ bo,
    float* __restrict__ cst, unsigned short* __restrict__ hf,
    float* __restrict__ out, int t, int gates)
{
    __shared__ float zs[4 * 260];
    const int bid = blockIdx.x, tid = threadIdx.x;
    const int lane = tid & 63, w = tid >> 6;

    if (gates && bid < 256) {
        const int m = bid >> 2, jc = (bid & 3) << 8;
        // wave w sums gate w over SK slices (coalesced along j)
        for (int rep = 0; rep < 4; ++rep) {
            const int j = jc + rep * 64 + lane;
            float sum = 0.f;
            #pragma unroll
            for (int sI = 0; sI < SK; ++sI)
                sum += zpart[((size_t)(sI * 64 + m)) * NG + w * NH + j];
            zs[w * 260 + rep * 64 + lane] = sum;
        }
        __syncthreads();
        {
            const int jl = tid, j = jc + jl;
            float zi = zs[0 * 260 + jl] + bias[j];
            float zf = zs[1 * 260 + jl] + bias[NH + j];
            float zg = zs[2 * 260 + jl] + bias[2 * NH + j];
            float zo = zs[3 * 260 + jl] + bias[3 * NH + j];
            float iv = sigf(zi), fv = sigf(zf), gv = tanhf(zg), ov = sigf(zo);
            const size_t ci = (size_t)m * NH + j;
            float cv = fv * cst[ci] + iv * gv;
            cst[ci] = cv;
            float hv = ov * tanhf(cv);
            float back;
            unsigned short h0 = bf_hi(hv, &back);
            unsigned short h1 = bf_hi(hv - back, &back);
            const int nbuf = (t + 1) & 1;
            int ku = j >> 5, kr = j & 31, mb2 = m >> 4;
            int lane2 = (kr >> 3) * 16 + (m & 15), jj = kr & 7;
            size_t base = (((size_t)nbuf * 32 + ku) * 4 + mb2) * 512 + lane2 * 8 + jj;
            hf[base] = h0;
            hf[base + 131072] = h1;   // v=1 stride = 2*32*4*512
        }
    }

    const int ob = gates ? (bid - 256) : bid;
    if (ob >= 0 && ob < 32 && t >= 1) {
        const int b0 = ob * 512;
        #pragma unroll
        for (int rr = 0; rr < 2; ++rr) {
            const int e = b0 + rr * 256 + tid;
            const int m = e >> 8, oc = e & 255;
            float v = opart[(size_t)m * NDOUT + oc]
                    + opart[(size_t)(64 + m) * NDOUT + oc] + bo[oc];
            out[((size_t)m * NT + (t - 1)) * NDOUT + oc] = fmaxf(v, 0.f);
        }
    }
}

extern "C" void kernel_launch(void* const* d_in, const int* in_sizes, int n_in,
                              void* d_out, int out_size, void* d_ws, size_t ws_size,
                              hipStream_t stream) {
    const float* x  = (const float*)d_in[0];
    const float* Wx = (const float*)d_in[1];
    const float* Wh = (const float*)d_in[2];
    const float* b  = (const float*)d_in[3];
    const float* Wo = (const float*)d_in[4];
    const float* bo = (const float*)d_in[5];
    float* out = (float*)d_out;
    char* ws = (char*)d_ws;

    size_t off = 0;
    float* cst    = (float*)(ws + off);               off += (size_t)NB * NH * 4;               // 256 KB
    unsigned short* hf = (unsigned short*)(ws + off); off += (size_t)2 * 2 * 32 * 4 * 512 * 2;  // 512 KB
    size_t zero_floats = off / 4;                     // cst + hf zeroed
    float* opart = (float*)(ws + off);                off += (size_t)2 * NB * NDOUT * 4;        // 128 KB
    float* zpart = (float*)(ws + off);                off += (size_t)SK * NB * NG * 4;          // 15.75 MB
    unsigned short* W0f = (unsigned short*)(ws + off); off += (size_t)1280 * 4096 * 2;
    unsigned short* W1f = (unsigned short*)(ws + off); off += (size_t)1280 * 4096 * 2;
    unsigned short* Wo0f = (unsigned short*)(ws + off); off += (size_t)NH * NDOUT * 2;
    unsigned short* Wo1f = (unsigned short*)(ws + off); off += (size_t)NH * NDOUT * 2;
    unsigned short* xf0 = (unsigned short*)(ws + off); off += (size_t)NB * NT * NDIN * 2;
    unsigned short* xf1 = (unsigned short*)(ws + off); off += (size_t)NB * NT * NDIN * 2;

    zero_kernel<<<(int)((zero_floats + 255) / 256), 256, 0, stream>>>((float*)ws, (int)zero_floats);
    packW_kernel<<<(1280 * 4096 + 255) / 256, 256, 0, stream>>>(Wx, Wh, W0f, W1f);
    packX_kernel<<<(NB * NT * NDIN + 255) / 256, 256, 0, stream>>>(x, xf0, xf1);
    packWo_kernel<<<(NH * NDOUT + 255) / 256, 256, 0, stream>>>(Wo, Wo0f, Wo1f);

    for (int t = 0; t < NT; ++t) {
        lstm_a<<<GRIDA, 256, 0, stream>>>(W0f, W1f, xf0, xf1, Wo0f, Wo1f, hf,
                                          zpart, opart, t, 1);
        lstm_b<<<GRIDB, 256, 0, stream>>>(zpart, opart, b, bo, cst, hf, out, t, 1);
    }
    // tail: project h_512 (hf[0]) -> out row 511
    lstm_a<<<32, 256, 0, stream>>>(W0f, W1f, xf0, xf1, Wo0f, Wo1f, hf,
                                   zpart, opart, NT, 0);
    lstm_b<<<32, 256, 0, stream>>>(zpart, opart, b, bo, cst, hf, out, NT, 0);
}